// Round 2
// baseline (266.939 us; speedup 1.0000x reference)
//
#include <hip/hip_runtime.h>
#include <hip/hip_fp16.h>

#define HH 512
#define WW 1408
#define HWPIX (HH*WW)
#define NCH 17
#define NX 200
#define NY 200
#define NZ 16
#define NVOX (NX*NY*NZ)
#define NCAM 6
#define VOXSZ 0.4f
#define PCMINX (-40.0f)
#define PCMINY (-40.0f)
#define PCMINZ (-1.0f)
#define S2 (VOXSZ*VOXSZ)
#define TIX 20
#define NPREP_T (NY*10)            // transpose blocks in prep
#define LDSF_STRIDE 276            // 272 padded to float4 multiple
#define L2E 1.44269504f
#define NXBLK (HWPIX/256)          // 2816 pixel-blocks
#define XPXCD (NXBLK/8)            // 352 pixel-blocks per XCD band (64 rows)

union U4H8 { uint4 u; __half2 h2[4]; __half h[8]; };

// ---- prep: fp16 planar transpose (float4-vectorized, interleaved h4 layout)
//      + separable conic table build ----  (Round-1 version, validated absmax 0.0)
__global__ __launch_bounds__(256) void prep_kernel(
    const float* __restrict__ feats,
    const float* __restrict__ density,
    const float* __restrict__ viewmats,
    const float* __restrict__ Ks,
    uint4*  __restrict__ h4tab,           // NVOX records of 2x uint4, interleaved
    __half* __restrict__ h1tab,           // 1 plane  x NVOX half (ch16)
    float4* __restrict__ xtab,            // (NCAM,NZ,WW)
    float4* __restrict__ ytab,            // (NCAM,NZ,HH)
    float* __restrict__ accum)
{
    const int t = threadIdx.x;
    if (blockIdx.x < NPREP_T) {
        __shared__ float ldsF[TIX * LDSF_STRIDE];
        __shared__ float ldsD[TIX][NZ];
        const int iy     = blockIdx.x / 10;
        const int ixBase = (blockIdx.x % 10) * TIX;
        for (int q = t; q < TIX * 68; q += 256) {
            const int r = q / 68, j4 = q % 68;
            const float4 v = *reinterpret_cast<const float4*>(
                feats + ((size_t)(ixBase + r) * NY + iy) * 272 + j4 * 4);
            *reinterpret_cast<float4*>(&ldsF[r * LDSF_STRIDE + j4 * 4]) = v;
        }
        for (int q = t; q < TIX * 4; q += 256) {
            const int r = q / 4, jd = q % 4;
            const float4 v = *reinterpret_cast<const float4*>(
                density + ((size_t)(ixBase + r) * NY + iy) * NZ + jd * 4);
            *reinterpret_cast<float4*>(&ldsD[r][jd * 4]) = v;
        }
        __syncthreads();
        for (int q = t; q < TIX * NZ * 2; q += 256) {
            const int kg = q & 1;
            const int r  = (q >> 1) % TIX;
            const int iz = q / (2 * TIX);
            const float d = ldsD[r][iz];
            const int jb = r * LDSF_STRIDE + iz * NCH + kg * 8;
            U4H8 pk;
            #pragma unroll
            for (int i = 0; i < 8; ++i) pk.h[i] = __float2half(ldsF[jb + i] * d);
            h4tab[((size_t)(iz * NY + iy) * NX + ixBase + r) * 2 + kg] = pk.u;
        }
        for (int q = t; q < NZ * TIX; q += 256) {
            const int r  = q % TIX;
            const int iz = q / TIX;
            h1tab[(size_t)(iz * NY + iy) * NX + ixBase + r] =
                __float2half(ldsF[r * LDSF_STRIDE + iz * NCH + 16] * ldsD[r][iz]);
        }
        return;
    }

    const int bid = blockIdx.x - NPREP_T;
    if (bid == 0 && t < 16) accum[t] = 0.f;

    const int cam = bid / NZ;
    const int iz  = bid % NZ;
    const float* vm = viewmats + cam * 16;
    const float* K  = Ks + cam * 9;
    const float fx = K[0], fy = K[4], cx = K[2], cy = K[5];
    const float zw = PCMINZ + ((float)iz + 0.5f) * VOXSZ;
    const float pz = vm[10] * zw + vm[11];
    const bool layerok = pz > 0.1f;
    const float z = fmaxf(pz, 0.001f);
    const float invz = 1.0f / z;
    const float sk  = VOXSZ * invz;
    const float A0x = (VOXSZ * fx * invz) * (VOXSZ * fx * invz);
    const float A0y = (VOXSZ * fy * invz) * (VOXSZ * fy * invz);
    const float S0C = sqrtf(0.5f * L2E);

    for (int px = t; px < WW; px += blockDim.x) {
        const float xt = ((float)px - cx) * z / fx - vm[3];
        const int ixe = (int)rintf((xt - PCMINX) * 2.5f - 0.5f);
        int sel = -1; float usel = 0.f;
        for (int d = -1; d <= 1; ++d) {
            const int ix = ixe + d;
            const float xw = PCMINX + ((float)ix + 0.5f) * VOXSZ;
            const float pxc = vm[0] * xw + vm[3];
            const float u = fx * pxc * invz + cx;
            if (ix >= 0 && ix < NX && fabsf((float)px - rintf(u)) <= 1.0f) {
                sel = ix; usel = u;
            }
        }
        float4 e;
        if (sel >= 0 && layerok) {
            const float gx = cx - usel;
            const float sx = sk * gx;
            e = make_float4(((float)px - usel) * S0C, sx,
                            fmaf(sx, sx, A0x + 0.3f), __int_as_float(sel));
        } else {
            e = make_float4(0.f, 0.f, 1.f, __int_as_float(-1));
        }
        xtab[(cam * NZ + iz) * WW + px] = e;
    }
    for (int py = t; py < HH; py += blockDim.x) {
        const float yt = ((float)py - cy) * z / fy - vm[7];
        const int iye = (int)rintf((yt - PCMINY) * 2.5f - 0.5f);
        int sel = -1; float vsel = 0.f;
        for (int d = -1; d <= 1; ++d) {
            const int iy = iye + d;
            const float yw = PCMINY + ((float)iy + 0.5f) * VOXSZ;
            const float pyc = vm[5] * yw + vm[7];
            const float v = fy * pyc * invz + cy;
            if (iy >= 0 && iy < NY && fabsf((float)py - rintf(v)) <= 1.0f) {
                sel = iy; vsel = v;
            }
        }
        float4 e;
        if (sel >= 0 && layerok) {
            const float gy = cy - vsel;
            const float sy = sk * gy;
            e = make_float4(((float)py - vsel) * S0C, sy,
                            fmaf(sy, sy, A0y + 0.3f), __int_as_float(sel * NX));
        } else {
            e = make_float4(0.f, 0.f, 1.f, __int_as_float(-1));
        }
        ytab[(cam * NZ + iz) * HH + py] = e;
    }
}

// ---- fused gather + CE loss: depth-2 software pipeline + XCD-banded swizzle ----
// STAGE: compute wv/vi (branchless, clamped index) and ISSUE the 6 gathers.
// CONSUME: packed-fp16 FMA of a previously-staged set (loads long in flight).
#define STAGE(IZ, TX, TY, Pp0, Pp1, Pfs, Pwv)                                 \
    {                                                                         \
        const int izOff = (IZ) * (NY * NX);                                   \
        _Pragma("unroll")                                                     \
        for (int c2 = 0; c2 < 2; ++c2) {                                      \
            const float4 xe = TX[c2];  /* {du', sx, a, ix} */                 \
            const float4 ye = TY[c2];  /* {dv', sy, c, iy*NX} */              \
            const int ix   = __float_as_int(xe.w);                            \
            const int iyNX = __float_as_int(ye.w);                            \
            const bool cov = (ix | iyNX) >= 0;                                \
            const float bb  = xe.y * ye.y;                                    \
            const float det = fmaf(-bb, bb, xe.z * ye.z);                     \
            float num = fmaf(ye.z, xe.x * xe.x, xe.z * (ye.x * ye.x));        \
            num = fmaf(xe.x * ye.x, -(bb + bb), num);                         \
            const float w = __builtin_amdgcn_exp2f(-num * __builtin_amdgcn_rcpf(det)); \
            Pwv[c2] = cov ? w : 0.f;                                          \
            const int viL = cov ? izOff + iyNX + ix : 0;                      \
            const size_t h4i = (size_t)viL * 2;                               \
            Pp0[c2] = h4tab[h4i];                                             \
            Pp1[c2] = h4tab[h4i + 1];                                         \
            Pfs[c2] = h1tab[viL];                                             \
        }                                                                     \
    }

#define CONSUME(Pp0, Pp1, Pfs, Pwv)                                           \
    {                                                                         \
        _Pragma("unroll")                                                     \
        for (int c2 = 0; c2 < 2; ++c2) {                                      \
            const __half2 wh = __float2half2_rn(Pwv[c2]);                     \
            U4H8 q0, q1; q0.u = Pp0[c2]; q1.u = Pp1[c2];                      \
            _Pragma("unroll")                                                 \
            for (int i = 0; i < 4; ++i) {                                     \
                acc2[c2][i]   = __hfma2(wh, q0.h2[i], acc2[c2][i]);           \
                acc2[c2][4+i] = __hfma2(wh, q1.h2[i], acc2[c2][4+i]);         \
            }                                                                 \
            acc16[c2] = fmaf(Pwv[c2], __half2float(Pfs[c2]), acc16[c2]);      \
        }                                                                     \
    }

__global__ __launch_bounds__(256) void gather_loss_kernel(
    const uint4*  __restrict__ h4tab,
    const __half* __restrict__ h1tab,
    const float4* __restrict__ xtab,
    const float4* __restrict__ ytab,
    const int*    __restrict__ gt,
    const float*  __restrict__ cw,
    float* __restrict__ accum)            // (NCAM,2)
{
    // XCD-banded swizzle: XCD k (b%8 round-robin) owns a contiguous 64-row
    // py band (352 pixel-blocks) for ALL 3 cam-pairs -> per-XCD L2 footprint
    // ~1-2MB (fits 4MiB) instead of the full 20.5MB h4tab.
    const int b    = blockIdx.x;
    const int xcd  = b & 7;
    const int slot = b >> 3;
    const int pair = slot % 3;
    const int xloc = slot / 3;
    const int pix  = (xcd * XPXCD + xloc) * 256 + threadIdx.x;
    const int cam0 = pair * 2;

    const int px = pix % WW;
    const int py = pix / WW;              // wave-uniform: 1408 = 22*64

    // gt prefetch: issued first, consumed in epilogue
    const int g0 = gt[(size_t)(cam0 + 0) * HWPIX + pix];
    const int g1 = gt[(size_t)(cam0 + 1) * HWPIX + pix];

    const float4* xb0 = xtab + (size_t)((cam0 + 0) * NZ) * WW + px;
    const float4* xb1 = xtab + (size_t)((cam0 + 1) * NZ) * WW + px;
    const float4* yb0 = ytab + (size_t)((cam0 + 0) * NZ) * HH + py;
    const float4* yb1 = ytab + (size_t)((cam0 + 1) * NZ) * HH + py;

    __half2 acc2[2][8];
    float acc16[2] = {0.f, 0.f};
    #pragma unroll
    for (int c2 = 0; c2 < 2; ++c2)
        #pragma unroll
        for (int i = 0; i < 8; ++i) acc2[c2][i] = __float2half2_rn(0.f);

    uint4 Ap0[2], Ap1[2]; __half Afs[2]; float Awv[2];
    uint4 Bp0[2], Bp1[2]; __half Bfs[2]; float Bwv[2];
    float4 txA[2], tyA[2], txB[2], tyB[2];

    // prologue: stage iz=0 and iz=1 (12 gathers in flight before 1st consume)
    txA[0] = xb0[0]; txA[1] = xb1[0]; tyA[0] = yb0[0]; tyA[1] = yb1[0];
    STAGE(0, txA, tyA, Ap0, Ap1, Afs, Awv);
    txB[0] = xb0[WW]; txB[1] = xb1[WW]; tyB[0] = yb0[HH]; tyB[1] = yb1[HH];
    STAGE(1, txB, tyB, Bp0, Bp1, Bfs, Bwv);

    #pragma unroll 1
    for (int iz = 2; iz < NZ; iz += 2) {
        txA[0] = xb0[(size_t)iz * WW]; txA[1] = xb1[(size_t)iz * WW];
        tyA[0] = yb0[(size_t)iz * HH]; tyA[1] = yb1[(size_t)iz * HH];
        CONSUME(Ap0, Ap1, Afs, Awv);
        STAGE(iz, txA, tyA, Ap0, Ap1, Afs, Awv);
        txB[0] = xb0[(size_t)(iz + 1) * WW]; txB[1] = xb1[(size_t)(iz + 1) * WW];
        tyB[0] = yb0[(size_t)(iz + 1) * HH]; tyB[1] = yb1[(size_t)(iz + 1) * HH];
        CONSUME(Bp0, Bp1, Bfs, Bwv);
        STAGE(iz + 1, txB, tyB, Bp0, Bp1, Bfs, Bwv);
    }
    CONSUME(Ap0, Ap1, Afs, Awv);
    CONSUME(Bp0, Bp1, Bfs, Bwv);

    const int gsel[2] = {g0, g1};
    float wnll[2], wsum[2];
    #pragma unroll
    for (int c2 = 0; c2 < 2; ++c2) {
        float accf[NCH];
        #pragma unroll
        for (int i = 0; i < 8; ++i) {
            const float2 f2v = __half22float2(acc2[c2][i]);
            accf[2*i + 0] = f2v.x;
            accf[2*i + 1] = f2v.y;
        }
        accf[16] = acc16[c2];

        float m = accf[0];
        #pragma unroll
        for (int k = 1; k < NCH; ++k) m = fmaxf(m, accf[k]);
        const float mL = m * L2E;
        float s = 0.f;
        #pragma unroll
        for (int k = 0; k < NCH; ++k)
            s += __builtin_amdgcn_exp2f(fmaf(accf[k], L2E, -mL));
        const float lse = m + 0.69314718f * __builtin_amdgcn_logf(s);

        const int g = gsel[c2];
        float selLogit = 0.f;
        #pragma unroll
        for (int k = 0; k < NCH; ++k)
            selLogit = (g == k) ? accf[k] : selLogit;   // static cndmask chain

        const float wvt = (g != 0) ? cw[g] : 0.f;
        wnll[c2] = wvt * (lse - selLogit);
        wsum[c2] = wvt;
    }

    #pragma unroll
    for (int off = 32; off > 0; off >>= 1) {
        #pragma unroll
        for (int c2 = 0; c2 < 2; ++c2) {
            wnll[c2] += __shfl_down(wnll[c2], off);
            wsum[c2] += __shfl_down(wsum[c2], off);
        }
    }
    __shared__ float red[4][4];
    const int wave = threadIdx.x >> 6, lane = threadIdx.x & 63;
    if (lane == 0) {
        #pragma unroll
        for (int c2 = 0; c2 < 2; ++c2) {
            red[wave][c2 * 2 + 0] = wnll[c2];
            red[wave][c2 * 2 + 1] = wsum[c2];
        }
    }
    __syncthreads();
    if (threadIdx.x < 4) {
        const float v = red[0][threadIdx.x] + red[1][threadIdx.x] +
                        red[2][threadIdx.x] + red[3][threadIdx.x];
        atomicAdd(&accum[cam0 * 2 + threadIdx.x], v);
    }
}

__global__ void finalize_kernel(const float* __restrict__ accum, float* __restrict__ out)
{
    if (threadIdx.x == 0 && blockIdx.x == 0) {
        float loss = 0.f;
        for (int c = 0; c < NCAM; ++c)
            loss += accum[c * 2 + 0] / fmaxf(accum[c * 2 + 1], 1e-8f);
        out[0] = loss / (float)NCAM;   // B == 1
    }
}

extern "C" void kernel_launch(void* const* d_in, const int* in_sizes, int n_in,
                              void* d_out, int out_size, void* d_ws, size_t ws_size,
                              hipStream_t stream)
{
    const float* voxel_feats = (const float*)d_in[0];
    const float* density     = (const float*)d_in[1];
    const float* viewmats    = (const float*)d_in[2];
    const float* Ks          = (const float*)d_in[3];
    const int*   gt_sem      = (const int*)  d_in[4];
    const float* pc_xyz      = (const float*)d_in[5];  (void)pc_xyz;
    const float* cw          = (const float*)d_in[6];
    float* out = (float*)d_out;

    // ws: [accum 256B][xtab 2.16MB][ytab 0.79MB][h4tab 20.5MB][h1tab 1.3MB]
    char* w = (char*)d_ws;
    float*  accum = (float*)w;                          w += 256;
    float4* xtab  = (float4*)w;                         w += (size_t)NCAM * NZ * WW * sizeof(float4);
    float4* ytab  = (float4*)w;                         w += (size_t)NCAM * NZ * HH * sizeof(float4);
    uint4*  h4tab = (uint4*)w;                          w += (size_t)2 * NVOX * sizeof(uint4);
    __half* h1tab = (__half*)w;

    prep_kernel<<<NPREP_T + NCAM * NZ, 256, 0, stream>>>(
        voxel_feats, density, viewmats, Ks, h4tab, h1tab,
        xtab, ytab, accum);

    gather_loss_kernel<<<NXBLK * 3, 256, 0, stream>>>(h4tab, h1tab, xtab, ytab,
                                                      gt_sem, cw, accum);
    finalize_kernel<<<1, 64, 0, stream>>>(accum, out);
}

// Round 3
// 235.478 us; speedup vs baseline: 1.1336x; 1.1336x over previous
//
#include <hip/hip_runtime.h>
#include <hip/hip_fp16.h>

#define HH 512
#define WW 1408
#define HWPIX (HH*WW)
#define NCH 17
#define NX 200
#define NY 200
#define NZ 16
#define NVOX (NX*NY*NZ)
#define NCAM 6
#define VOXSZ 0.4f
#define PCMINX (-40.0f)
#define PCMINY (-40.0f)
#define PCMINZ (-1.0f)
#define S2 (VOXSZ*VOXSZ)
#define TIX 20
#define NPREP_T (NY*10)            // transpose blocks
#define LDSF_STRIDE 276            // 272 padded to float4 multiple
#define L2E 1.44269504f
#define NXBLK (HWPIX/256)          // 2816 pixel-blocks
#define XPXCD (NXBLK/8)            // 352 pixel-blocks per XCD band

union U4H8 { uint4 u; __half2 h2[4]; __half h[8]; };

// ---- prep A: fp16 planar transpose (float4-vectorized, interleaved h4) ----
__global__ __launch_bounds__(256) void prep_transpose_kernel(
    const float* __restrict__ feats,
    const float* __restrict__ density,
    uint4*  __restrict__ h4tab,           // NVOX records of 2x uint4, interleaved
    __half* __restrict__ h1tab)           // 1 plane x NVOX half (ch16)
{
    const int t = threadIdx.x;
    __shared__ float ldsF[TIX * LDSF_STRIDE];
    __shared__ float ldsD[TIX][NZ];
    const int iy     = blockIdx.x / 10;
    const int ixBase = (blockIdx.x % 10) * TIX;
    for (int q = t; q < TIX * 68; q += 256) {
        const int r = q / 68, j4 = q % 68;
        const float4 v = *reinterpret_cast<const float4*>(
            feats + ((size_t)(ixBase + r) * NY + iy) * 272 + j4 * 4);
        *reinterpret_cast<float4*>(&ldsF[r * LDSF_STRIDE + j4 * 4]) = v;
    }
    for (int q = t; q < TIX * 4; q += 256) {
        const int r = q / 4, jd = q % 4;
        const float4 v = *reinterpret_cast<const float4*>(
            density + ((size_t)(ixBase + r) * NY + iy) * NZ + jd * 4);
        *reinterpret_cast<float4*>(&ldsD[r][jd * 4]) = v;
    }
    __syncthreads();
    for (int q = t; q < TIX * NZ * 2; q += 256) {
        const int kg = q & 1;
        const int r  = (q >> 1) % TIX;
        const int iz = q / (2 * TIX);
        const float d = ldsD[r][iz];
        const int jb = r * LDSF_STRIDE + iz * NCH + kg * 8;
        U4H8 pk;
        #pragma unroll
        for (int i = 0; i < 8; ++i) pk.h[i] = __float2half(ldsF[jb + i] * d);
        h4tab[((size_t)(iz * NY + iy) * NX + ixBase + r) * 2 + kg] = pk.u;
    }
    // ch16 plane, paired half2 stores (even index -> 4B aligned)
    for (int q = t; q < NZ * (TIX / 2); q += 256) {
        const int rp = (q % (TIX / 2)) * 2;
        const int iz = q / (TIX / 2);
        __half2 hv;
        hv.x = __float2half(ldsF[rp * LDSF_STRIDE + iz * NCH + 16] * ldsD[rp][iz]);
        hv.y = __float2half(ldsF[(rp + 1) * LDSF_STRIDE + iz * NCH + 16] * ldsD[rp + 1][iz]);
        *reinterpret_cast<__half2*>(
            &h1tab[(size_t)(iz * NY + iy) * NX + ixBase + rp]) = hv;
    }
}

// ---- prep B: separable conic tables + px any-coverage map ----
// xtab[cam,iz,px] = {du*s0, sx, a, ix_bits}      (s0 = sqrt(0.5*log2e))
// ytab[cam,iz,py] = {dv*s0, sy, c, (iy*NX)_bits}
__global__ __launch_bounds__(256) void prep_tables_kernel(
    const float* __restrict__ viewmats,
    const float* __restrict__ Ks,
    float4* __restrict__ xtab,            // (NCAM,NZ,WW)
    float4* __restrict__ ytab,            // (NCAM,NZ,HH)
    unsigned int* __restrict__ pxany)     // (NCAM,WW) any-iz coverage
{
    const int t = threadIdx.x;
    const int cam = blockIdx.x / NZ;
    const int iz  = blockIdx.x % NZ;
    const float* vm = viewmats + cam * 16;
    const float* K  = Ks + cam * 9;
    const float fx = K[0], fy = K[4], cx = K[2], cy = K[5];
    const float zw = PCMINZ + ((float)iz + 0.5f) * VOXSZ;
    const float pz = vm[10] * zw + vm[11];
    const bool layerok = pz > 0.1f;
    const float z = fmaxf(pz, 0.001f);
    const float invz = 1.0f / z;
    const float sk  = VOXSZ * invz;
    const float A0x = (VOXSZ * fx * invz) * (VOXSZ * fx * invz);
    const float A0y = (VOXSZ * fy * invz) * (VOXSZ * fy * invz);
    const float S0C = sqrtf(0.5f * L2E);

    for (int px = t; px < WW; px += blockDim.x) {
        const float xt = ((float)px - cx) * z / fx - vm[3];
        const int ixe = (int)rintf((xt - PCMINX) * 2.5f - 0.5f);
        int sel = -1; float usel = 0.f;
        for (int d = -1; d <= 1; ++d) {
            const int ix = ixe + d;
            const float xw = PCMINX + ((float)ix + 0.5f) * VOXSZ;
            const float pxc = vm[0] * xw + vm[3];
            const float u = fx * pxc * invz + cx;
            if (ix >= 0 && ix < NX && fabsf((float)px - rintf(u)) <= 1.0f) {
                sel = ix; usel = u;
            }
        }
        float4 e;
        if (sel >= 0 && layerok) {
            const float gx = cx - usel;
            const float sx = sk * gx;
            e = make_float4(((float)px - usel) * S0C, sx,
                            fmaf(sx, sx, A0x + 0.3f), __int_as_float(sel));
            atomicOr(&pxany[cam * WW + px], 1u);
        } else {
            e = make_float4(0.f, 0.f, 1.f, __int_as_float(-1));
        }
        xtab[(cam * NZ + iz) * WW + px] = e;
    }
    for (int py = t; py < HH; py += blockDim.x) {
        const float yt = ((float)py - cy) * z / fy - vm[7];
        const int iye = (int)rintf((yt - PCMINY) * 2.5f - 0.5f);
        int sel = -1; float vsel = 0.f;
        for (int d = -1; d <= 1; ++d) {
            const int iy = iye + d;
            const float yw = PCMINY + ((float)iy + 0.5f) * VOXSZ;
            const float pyc = vm[5] * yw + vm[7];
            const float v = fy * pyc * invz + cy;
            if (iy >= 0 && iy < NY && fabsf((float)py - rintf(v)) <= 1.0f) {
                sel = iy; vsel = v;
            }
        }
        float4 e;
        if (sel >= 0 && layerok) {
            const float gy = cy - vsel;
            const float sy = sk * gy;
            e = make_float4(((float)py - vsel) * S0C, sy,
                            fmaf(sy, sy, A0y + 0.3f), __int_as_float(sel * NX));
        } else {
            e = make_float4(0.f, 0.f, 1.f, __int_as_float(-1));
        }
        ytab[(cam * NZ + iz) * HH + py] = e;
    }
}

// ---- fused gather + CE loss: guarded depth-2 pipeline + XCD band + wave cull ----
// STAGE: compute wv (0 if uncovered); ISSUE gathers only for covered lanes.
// CONSUME: FMA only where wv>0 (skips stale regs AND exact-zero adds).
#define STAGE(IZ, TX, TY, Pp0, Pp1, Pfs, Pwv)                                 \
    {                                                                         \
        const int izOff = (IZ) * (NY * NX);                                   \
        _Pragma("unroll")                                                     \
        for (int c2 = 0; c2 < 2; ++c2) {                                      \
            const float4 xe = TX[c2];  /* {du', sx, a, ix} */                 \
            const float4 ye = TY[c2];  /* {dv', sy, c, iy*NX} */              \
            const int ix   = __float_as_int(xe.w);                            \
            const int iyNX = __float_as_int(ye.w);                            \
            const bool cov = (ix | iyNX) >= 0;                                \
            const float bb  = xe.y * ye.y;                                    \
            const float det = fmaf(-bb, bb, xe.z * ye.z);                     \
            float num = fmaf(ye.z, xe.x * xe.x, xe.z * (ye.x * ye.x));        \
            num = fmaf(xe.x * ye.x, -(bb + bb), num);                         \
            const float w = __builtin_amdgcn_exp2f(-num * __builtin_amdgcn_rcpf(det)); \
            Pwv[c2] = cov ? w : 0.f;                                          \
            if (cov) {                                                        \
                const size_t h4i = (size_t)(izOff + iyNX + ix) * 2;           \
                Pp0[c2] = h4tab[h4i];                                         \
                Pp1[c2] = h4tab[h4i + 1];                                     \
                Pfs[c2] = h1tab[izOff + iyNX + ix];                           \
            }                                                                 \
        }                                                                     \
    }

#define CONSUME(Pp0, Pp1, Pfs, Pwv)                                           \
    {                                                                         \
        _Pragma("unroll")                                                     \
        for (int c2 = 0; c2 < 2; ++c2) {                                      \
            if (Pwv[c2] > 0.f) {                                              \
                const __half2 wh = __float2half2_rn(Pwv[c2]);                 \
                U4H8 q0, q1; q0.u = Pp0[c2]; q1.u = Pp1[c2];                  \
                _Pragma("unroll")                                             \
                for (int i = 0; i < 4; ++i) {                                 \
                    acc2[c2][i]   = __hfma2(wh, q0.h2[i], acc2[c2][i]);       \
                    acc2[c2][4+i] = __hfma2(wh, q1.h2[i], acc2[c2][4+i]);     \
                }                                                             \
                acc16[c2] = fmaf(Pwv[c2], __half2float(Pfs[c2]), acc16[c2]);  \
            }                                                                 \
        }                                                                     \
    }

__global__ __launch_bounds__(256) void gather_loss_kernel(
    const uint4*  __restrict__ h4tab,
    const __half* __restrict__ h1tab,
    const float4* __restrict__ xtab,
    const float4* __restrict__ ytab,
    const unsigned int* __restrict__ pxany,
    const int*    __restrict__ gt,
    const float*  __restrict__ cw,
    float* __restrict__ accum)            // (NCAM,2)
{
    // XCD-banded swizzle (kept from R2: FETCH 85MB -> 24MB).
    const int b    = blockIdx.x;
    const int xcd  = b & 7;
    const int slot = b >> 3;
    const int pair = slot % 3;
    const int xloc = slot / 3;
    const int pix  = (xcd * XPXCD + xloc) * 256 + threadIdx.x;
    const int cam0 = pair * 2;

    const int px = pix % WW;
    const int py = pix / WW;
    const int pyw = __builtin_amdgcn_readfirstlane(py); // wave-uniform (1408=22*64)

    const int g0 = gt[(size_t)(cam0 + 0) * HWPIX + pix];
    const int g1 = gt[(size_t)(cam0 + 1) * HWPIX + pix];

    __half2 acc2[2][8];
    float acc16[2] = {0.f, 0.f};
    #pragma unroll
    for (int c2 = 0; c2 < 2; ++c2)
        #pragma unroll
        for (int i = 0; i < 8; ++i) acc2[c2][i] = __float2half2_rn(0.f);

    // wave-level coverage cull: ~1/3 of waves have no x-coverage in either cam
    const unsigned int cany = pxany[(cam0 + 0) * WW + px] |
                              pxany[(cam0 + 1) * WW + px];
    if (__any((int)(cany != 0))) {
        const float4* xb0 = xtab + (size_t)((cam0 + 0) * NZ) * WW + px;
        const float4* xb1 = xtab + (size_t)((cam0 + 1) * NZ) * WW + px;
        const float4* yb0 = ytab + (size_t)((cam0 + 0) * NZ) * HH + pyw;
        const float4* yb1 = ytab + (size_t)((cam0 + 1) * NZ) * HH + pyw;

        uint4 Ap0[2], Ap1[2]; __half Afs[2]; float Awv[2];
        uint4 Bp0[2], Bp1[2]; __half Bfs[2]; float Bwv[2];
        float4 txA[2], tyA[2], txB[2], tyB[2];

        txA[0] = xb0[0]; txA[1] = xb1[0]; tyA[0] = yb0[0]; tyA[1] = yb1[0];
        STAGE(0, txA, tyA, Ap0, Ap1, Afs, Awv);
        txB[0] = xb0[WW]; txB[1] = xb1[WW]; tyB[0] = yb0[HH]; tyB[1] = yb1[HH];
        STAGE(1, txB, tyB, Bp0, Bp1, Bfs, Bwv);

        #pragma unroll 1
        for (int iz = 2; iz < NZ; iz += 2) {
            txA[0] = xb0[(size_t)iz * WW]; txA[1] = xb1[(size_t)iz * WW];
            tyA[0] = yb0[(size_t)iz * HH]; tyA[1] = yb1[(size_t)iz * HH];
            CONSUME(Ap0, Ap1, Afs, Awv);
            STAGE(iz, txA, tyA, Ap0, Ap1, Afs, Awv);
            txB[0] = xb0[(size_t)(iz + 1) * WW]; txB[1] = xb1[(size_t)(iz + 1) * WW];
            tyB[0] = yb0[(size_t)(iz + 1) * HH]; tyB[1] = yb1[(size_t)(iz + 1) * HH];
            CONSUME(Bp0, Bp1, Bfs, Bwv);
            STAGE(iz + 1, txB, tyB, Bp0, Bp1, Bfs, Bwv);
        }
        CONSUME(Ap0, Ap1, Afs, Awv);
        CONSUME(Bp0, Bp1, Bfs, Bwv);
    }

    const int gsel[2] = {g0, g1};
    float wnll[2], wsum[2];
    #pragma unroll
    for (int c2 = 0; c2 < 2; ++c2) {
        float accf[NCH];
        #pragma unroll
        for (int i = 0; i < 8; ++i) {
            const float2 f2v = __half22float2(acc2[c2][i]);
            accf[2*i + 0] = f2v.x;
            accf[2*i + 1] = f2v.y;
        }
        accf[16] = acc16[c2];

        float m = accf[0];
        #pragma unroll
        for (int k = 1; k < NCH; ++k) m = fmaxf(m, accf[k]);
        const float mL = m * L2E;
        float s = 0.f;
        #pragma unroll
        for (int k = 0; k < NCH; ++k)
            s += __builtin_amdgcn_exp2f(fmaf(accf[k], L2E, -mL));
        const float lse = m + 0.69314718f * __builtin_amdgcn_logf(s);

        const int g = gsel[c2];
        float selLogit = 0.f;
        #pragma unroll
        for (int k = 0; k < NCH; ++k)
            selLogit = (g == k) ? accf[k] : selLogit;

        const float wvt = (g != 0) ? cw[g] : 0.f;
        wnll[c2] = wvt * (lse - selLogit);
        wsum[c2] = wvt;
    }

    #pragma unroll
    for (int off = 32; off > 0; off >>= 1) {
        #pragma unroll
        for (int c2 = 0; c2 < 2; ++c2) {
            wnll[c2] += __shfl_down(wnll[c2], off);
            wsum[c2] += __shfl_down(wsum[c2], off);
        }
    }
    __shared__ float red[4][4];
    const int wave = threadIdx.x >> 6, lane = threadIdx.x & 63;
    if (lane == 0) {
        #pragma unroll
        for (int c2 = 0; c2 < 2; ++c2) {
            red[wave][c2 * 2 + 0] = wnll[c2];
            red[wave][c2 * 2 + 1] = wsum[c2];
        }
    }
    __syncthreads();
    if (threadIdx.x < 4) {
        const float v = red[0][threadIdx.x] + red[1][threadIdx.x] +
                        red[2][threadIdx.x] + red[3][threadIdx.x];
        atomicAdd(&accum[cam0 * 2 + threadIdx.x], v);
    }
}

__global__ void finalize_kernel(const float* __restrict__ accum, float* __restrict__ out)
{
    if (threadIdx.x == 0 && blockIdx.x == 0) {
        float loss = 0.f;
        for (int c = 0; c < NCAM; ++c)
            loss += accum[c * 2 + 0] / fmaxf(accum[c * 2 + 1], 1e-8f);
        out[0] = loss / (float)NCAM;   // B == 1
    }
}

extern "C" void kernel_launch(void* const* d_in, const int* in_sizes, int n_in,
                              void* d_out, int out_size, void* d_ws, size_t ws_size,
                              hipStream_t stream)
{
    const float* voxel_feats = (const float*)d_in[0];
    const float* density     = (const float*)d_in[1];
    const float* viewmats    = (const float*)d_in[2];
    const float* Ks          = (const float*)d_in[3];
    const int*   gt_sem      = (const int*)  d_in[4];
    const float* pc_xyz      = (const float*)d_in[5];  (void)pc_xyz;
    const float* cw          = (const float*)d_in[6];
    float* out = (float*)d_out;

    // ws: [accum 256B][pxany 33KB][xtab 2.16MB][ytab 0.79MB][h4tab 20.5MB][h1tab 1.3MB]
    char* w = (char*)d_ws;
    float*        accum = (float*)w;                    w += 256;
    unsigned int* pxany = (unsigned int*)w;             w += (size_t)NCAM * WW * sizeof(unsigned int);
    float4* xtab  = (float4*)w;                         w += (size_t)NCAM * NZ * WW * sizeof(float4);
    float4* ytab  = (float4*)w;                         w += (size_t)NCAM * NZ * HH * sizeof(float4);
    uint4*  h4tab = (uint4*)w;                          w += (size_t)2 * NVOX * sizeof(uint4);
    __half* h1tab = (__half*)w;

    hipMemsetAsync(d_ws, 0, 256 + (size_t)NCAM * WW * sizeof(unsigned int), stream);

    prep_transpose_kernel<<<NPREP_T, 256, 0, stream>>>(
        voxel_feats, density, h4tab, h1tab);
    prep_tables_kernel<<<NCAM * NZ, 256, 0, stream>>>(
        viewmats, Ks, xtab, ytab, pxany);

    gather_loss_kernel<<<NXBLK * 3, 256, 0, stream>>>(h4tab, h1tab, xtab, ytab,
                                                      pxany, gt_sem, cw, accum);
    finalize_kernel<<<1, 64, 0, stream>>>(accum, out);
}